// Round 11
// baseline (131.125 us; speedup 1.0000x reference)
//
#include <hip/hip_runtime.h>
#include <hip/hip_bf16.h>

#define D 128
#define TPW 8                 // 16-row tiles per wave
#define ROWS_PER_BLOCK 256    // 2 row-groups x 128 rows; grid 512

typedef __attribute__((ext_vector_type(8))) short short8;
typedef __attribute__((ext_vector_type(4))) float float4_t;

// ---------------------------------------------------------------------------
// Kernel 1: fold the 4 candidate ops into one combined matrix/bias.
// (R8 proved folding this into the gemm costs ~24us; keep it separate.)
// ---------------------------------------------------------------------------
__global__ void combine_kernel(const float* __restrict__ W,
                               const float* __restrict__ b,
                               const float* __restrict__ wts,
                               __hip_bfloat16* __restrict__ Wc,
                               float* __restrict__ bc) {
    int idx = blockIdx.x * blockDim.x + threadIdx.x;
    float w0 = wts[0], w1 = wts[1], w2 = wts[2], w3 = wts[3];
    if (idx < D * D) {
        float v = w0 * W[idx] + w1 * W[D * D + idx]
                + w2 * W[2 * D * D + idx] + w3 * W[3 * D * D + idx];
        Wc[idx] = __float2bfloat16(v);
    }
    if (idx < D) {
        bc[idx] = w0 * b[idx] + w1 * b[D + idx] + w2 * b[2 * D + idx] + w3 * b[3 * D + idx];
    }
}

__device__ __forceinline__ short8 cvt8_bf16(float4_t a, float4_t b) {
    union { short8 s; __hip_bfloat16 h[8]; } u;
    u.h[0] = __float2bfloat16(a[0]);
    u.h[1] = __float2bfloat16(a[1]);
    u.h[2] = __float2bfloat16(a[2]);
    u.h[3] = __float2bfloat16(a[3]);
    u.h[4] = __float2bfloat16(b[0]);
    u.h[5] = __float2bfloat16(b[1]);
    u.h[6] = __float2bfloat16(b[2]);
    u.h[7] = __float2bfloat16(b[3]);
    return u.s;
}

// Inline-asm global loads: volatile + memory clobber => cannot be sunk,
// rematerialized, or reordered (the R3 failure mode: plain-load register
// prefetches were sunk back to their uses, collapsing pipeline depth).
// All kernel loads go through asm, so the compiler's waitcnt pass owns no
// loads and cannot inject a serializing vmcnt(0) into the loop.
#define GLOAD16(dst, p) \
    asm volatile("global_load_dwordx4 %0, %1, off" : "=v"(dst) : "v"(p) : "memory")

// ---------------------------------------------------------------------------
// Kernel 2: y[m][f] = sum_d x[m][d] * Wc[f][d] + bc[f]   (M = 131072)
//
// LDS-FREE direct-to-register pipeline (hardened depth-2 resubmit of R10;
// R10's run died in the container — suspect regalloc pressure from the
// depth-3 ring, so B2 is dropped: ~195 VGPR, 2 waves/SIMD, grid exactly
// resident at 512 blocks x 4 waves).
//
// Per lane the MFMA B-frag for a 16-row tile is x[m0+r][ks*32+quad*8..+7]
// — 4x 32 contiguous bytes: no LDS staging needed at all. Each wave is
// fully independent (no barriers, no LDS, self-paced on counted vmcnt):
// 4 waves/block = 2 row-groups x 2 col-halves; 8 tiles x 16 rows/wave;
// depth-2 register ring B0/B1 (8 dwordx4 each, asm-pinned).
//
// vmcnt audit (in-order retirement; refill(T+2)=8 loads issued inside
// step T; 4 stores/step; prologue order wf(16),bias(4),R0(8),R1(8)):
//   ops younger than tile T's refill at step T's vwait:
//   T0: R1 = 8                     T1: R2+st0 = 12
//   T2: st0+R3+st1 = 16            T3: st1+R4+st2 = 16
//   T4: st2+R5+st3 = 16            T5: st3+R6+st4 = 16
//   T6: st4+R7+st5 = 16            T7: st5+st6 = 8
// Counted, never 0 mid-loop. sched_barrier(0) after each vwait stops
// register-only cvt/MFMA hoisting above it (rule #18). Stores read their
// registers at issue, so plain stores need no extra waits.
// ---------------------------------------------------------------------------
__global__ __launch_bounds__(256, 1) void gemm_kernel(const float* __restrict__ x,
                                                      const __hip_bfloat16* __restrict__ Wc,
                                                      const float* __restrict__ bc,
                                                      float* __restrict__ y, int M) {
    const int tid  = threadIdx.x;
    const int lane = tid & 63;
    const int wave = tid >> 6;
    const int r    = lane & 15;
    const int quad = lane >> 4;
    const int rg   = wave >> 1;   // row-group (128 rows each)
    const int chf  = wave & 1;    // col-half (64 of 128 f-columns)

    const int m0 = blockIdx.x * ROWS_PER_BLOCK + rg * 128;
    if (m0 >= M) return;

    // ---- Wc fragments (bf16) -> registers via asm (16 loads) ----
    short8 wf[4][4];
    #pragma unroll
    for (int f = 0; f < 4; f++)
        #pragma unroll
        for (int ks = 0; ks < 4; ks++) {
            const short* wp = (const short*)Wc
                + (chf * 64 + f * 16 + r) * D + ks * 32 + quad * 8;
            GLOAD16(wf[f][ks], wp);
        }

    // ---- bias -> registers via asm (4 loads) ----
    float4_t bias[4];
    #pragma unroll
    for (int f = 0; f < 4; f++) {
        const float* bp = bc + chf * 64 + f * 16 + quad * 4;
        GLOAD16(bias[f], bp);
    }

    // per-lane x base: row m0+r, cols quad*8..; tile t adds t*16*D floats
    const float* xl = x + (size_t)(m0 + r) * D + quad * 8;

    float4_t B0[8], B1[8];

#define REFILL(BUF, t) {                                                        \
        const float* tp = xl + (t) * 16 * D;                                    \
        _Pragma("unroll")                                                       \
        for (int ks = 0; ks < 4; ks++) {                                        \
            GLOAD16(BUF[2 * ks],     tp + ks * 32);                             \
            GLOAD16(BUF[2 * ks + 1], tp + ks * 32 + 4);                         \
        }                                                                       \
    }

    // ---- prologue: depth-2 ----
    REFILL(B0, 0)
    REFILL(B1, 1)

#define STEP(T, BUF, NW) {                                                      \
        asm volatile("s_waitcnt vmcnt(%0)" :: "i"(NW) : "memory");              \
        __builtin_amdgcn_sched_barrier(0);                                      \
        short8 xf[4];                                                           \
        _Pragma("unroll")                                                       \
        for (int ks = 0; ks < 4; ks++)                                          \
            xf[ks] = cvt8_bf16(BUF[2 * ks], BUF[2 * ks + 1]);                   \
        if ((T) + 2 < TPW) REFILL(BUF, (T) + 2)                                 \
        float4_t acc[4];                                                        \
        _Pragma("unroll")                                                       \
        for (int f = 0; f < 4; f++) acc[f] = bias[f];                           \
        _Pragma("unroll")                                                       \
        for (int ks = 0; ks < 4; ks++) {                                        \
            _Pragma("unroll")                                                   \
            for (int f = 0; f < 4; f++)                                         \
                acc[f] = __builtin_amdgcn_mfma_f32_16x16x32_bf16(               \
                    wf[f][ks], xf[ks], acc[f], 0, 0, 0);                        \
        }                                                                       \
        float* yp = y + (size_t)(m0 + (T) * 16 + r) * D + chf * 64 + quad * 4;  \
        _Pragma("unroll")                                                       \
        for (int f = 0; f < 4; f++)                                             \
            *(float4_t*)(yp + f * 16) = acc[f];                                 \
    }

    STEP(0, B0, 8)
    STEP(1, B1, 12)
    STEP(2, B0, 16)
    STEP(3, B1, 16)
    STEP(4, B0, 16)
    STEP(5, B1, 16)
    STEP(6, B0, 16)
    STEP(7, B1, 8)
#undef STEP
#undef REFILL
}

extern "C" void kernel_launch(void* const* d_in, const int* in_sizes, int n_in,
                              void* d_out, int out_size, void* d_ws, size_t ws_size,
                              hipStream_t stream) {
    const float* x   = (const float*)d_in[0];   // (B,S,D) fp32
    const float* W   = (const float*)d_in[1];   // (NOPS,D,D) fp32
    const float* b   = (const float*)d_in[2];   // (NOPS,D) fp32
    const float* wts = (const float*)d_in[3];   // (NOPS,) fp32
    float* y = (float*)d_out;

    __hip_bfloat16* Wc = (__hip_bfloat16*)d_ws;
    float* bc = (float*)((char*)d_ws + D * D * sizeof(__hip_bfloat16));

    combine_kernel<<<(D * D + 255) / 256, 256, 0, stream>>>(W, b, wts, Wc, bc);

    const int M = in_sizes[0] / D;  // B*S = 131072
    gemm_kernel<<<M / ROWS_PER_BLOCK, 256, 0, stream>>>(x, Wc, bc, y, M);
}